// Round 13
// baseline (174.349 us; speedup 1.0000x reference)
//
#include <hip/hip_runtime.h>
#include <math.h>

#define BB 32
#define VV 2048
#define PP 64
#define AA 8
#define NFF 128
#define FF 72          // P + A
#define TWOF 144       // 2*F

// ---------------------------------------------------------------------------
// k1: feats = [x@W1+b1, exp(-|x@W2+b2|)]  -> featsT [B][F][V], agg [B][V][A]
// (unchanged — cross-round stability control)
// ---------------------------------------------------------------------------
__global__ __launch_bounds__(256) void k1_feats(
        const float* __restrict__ x,
        const float* __restrict__ W1, const float* __restrict__ b1,
        const float* __restrict__ W2, const float* __restrict__ b2,
        float* __restrict__ featsT, float* __restrict__ agg) {
    const int b    = blockIdx.y;
    const int t    = threadIdx.x;
    const int w    = __builtin_amdgcn_readfirstlane(t >> 6);  // wave id, uniform
    const int lane = t & 63;
    const int v    = blockIdx.x * 64 + lane;

    float xs[64];
    const float4* xp = reinterpret_cast<const float4*>(x + ((size_t)b * VV + v) * PP);
    #pragma unroll
    for (int i = 0; i < 16; ++i) {
        float4 t4 = xp[i];
        xs[4 * i + 0] = t4.x; xs[4 * i + 1] = t4.y; xs[4 * i + 2] = t4.z; xs[4 * i + 3] = t4.w;
    }

    #pragma unroll 1
    for (int k = 0; k < 5; ++k) {
        const int c = w + 4 * k;           // uniform across wave
        if (c >= 18) break;                // uniform branch
        const int f0 = 4 * c;
        float4 acc;
        if (c < 16) {
            acc = make_float4(b1[f0 + 0], b1[f0 + 1], b1[f0 + 2], b1[f0 + 3]);
            #pragma unroll
            for (int p = 0; p < 64; ++p) {
                const float4 wt = *reinterpret_cast<const float4*>(&W1[p * 64 + f0]);
                const float xv = xs[p];
                acc.x += xv * wt.x; acc.y += xv * wt.y; acc.z += xv * wt.z; acc.w += xv * wt.w;
            }
        } else {
            const int a0 = f0 - 64;        // 0 or 4
            acc = make_float4(b2[a0 + 0], b2[a0 + 1], b2[a0 + 2], b2[a0 + 3]);
            #pragma unroll
            for (int p = 0; p < 64; ++p) {
                const float4 wt = *reinterpret_cast<const float4*>(&W2[p * 8 + a0]);
                const float xv = xs[p];
                acc.x += xv * wt.x; acc.y += xv * wt.y; acc.z += xv * wt.z; acc.w += xv * wt.w;
            }
            acc.x = __expf(-fabsf(acc.x));
            acc.y = __expf(-fabsf(acc.y));
            acc.z = __expf(-fabsf(acc.z));
            acc.w = __expf(-fabsf(acc.w));
            float4* ap = reinterpret_cast<float4*>(agg + ((size_t)b * VV + v) * AA);
            ap[c - 16] = acc;
        }
        float* fr = featsT + ((size_t)b * FF + f0) * VV + v;
        fr[0 * VV] = acc.x; fr[1 * VV] = acc.y; fr[2 * VV] = acc.z; fr[3 * VV] = acc.w;
    }
}

// ---------------------------------------------------------------------------
// k2: PARTIAL reduce over half of V -> part [2][B][A][2F]
// blockIdx.x = fg*2 + vhalf: 36 x 32 = 1152 blocks (4.5/CU, was 2.25/CU).
// Each block reduces 1024 vertices (4 iters); writes unscaled max / sum.
// ---------------------------------------------------------------------------
__global__ __launch_bounds__(256) void k2_reduce(
        const float* __restrict__ featsT, const float* __restrict__ agg,
        float* __restrict__ part) {
    const int bx = blockIdx.x;      // 0..35
    const int fg = bx >> 1;         // 0..17
    const int vh = bx & 1;          // 0/1: V-half
    const int b  = blockIdx.y;
    const int f0 = fg * 4;
    const int t  = threadIdx.x;
    const int wave = t >> 6, lane = t & 63;

    __shared__ float redm[4][32];
    __shared__ float reds[4][32];

    float pmax[4][8], psum[4][8];
    #pragma unroll
    for (int j = 0; j < 4; ++j)
        #pragma unroll
        for (int a = 0; a < 8; ++a) { pmax[j][a] = -INFINITY; psum[j][a] = 0.0f; }

    for (int i = 0; i < 4; ++i) {
        const int v = vh * 1024 + i * 256 + t;
        const float4* ep = reinterpret_cast<const float4*>(agg + ((size_t)b * VV + v) * AA);
        const float4 e0 = ep[0], e1 = ep[1];
        float e[8];
        e[0] = e0.x; e[1] = e0.y; e[2] = e0.z; e[3] = e0.w;
        e[4] = e1.x; e[5] = e1.y; e[6] = e1.z; e[7] = e1.w;
        #pragma unroll
        for (int j = 0; j < 4; ++j) {
            const float fv = featsT[((size_t)b * FF + f0 + j) * VV + v];
            #pragma unroll
            for (int a = 0; a < 8; ++a) {
                const float pr = e[a] * fv;
                pmax[j][a] = fmaxf(pmax[j][a], pr);
                psum[j][a] += pr;
            }
        }
    }

    #pragma unroll
    for (int j = 0; j < 4; ++j) {
        #pragma unroll
        for (int a = 0; a < 8; ++a) {
            float m = pmax[j][a];
            float s = psum[j][a];
            #pragma unroll
            for (int d = 1; d < 64; d <<= 1) {
                m = fmaxf(m, __shfl_xor(m, d));
                s += __shfl_xor(s, d);
            }
            if (lane == 0) { redm[wave][j * 8 + a] = m; reds[wave][j * 8 + a] = s; }
        }
    }
    __syncthreads();

    if (t < 32) {
        const int j = t >> 3, a = t & 7;
        float m = redm[0][t], s = reds[0][t];
        #pragma unroll
        for (int w = 1; w < 4; ++w) { m = fmaxf(m, redm[w][t]); s += reds[w][t]; }
        float* pr = part + (((size_t)vh * BB + b) * AA + a) * TWOF;
        pr[f0 + j]      = m;      // partial max (unscaled)
        pr[FF + f0 + j] = s;      // partial sum (unscaled)
    }
}

// ---------------------------------------------------------------------------
// k2b: combine the two V-half partials, then fold:
// M'[b][a][nf] = Wout[1216+a][nf] + sum_g comb[g]*Wout[64+a*144+g][nf]
// comb[g] = max(p0[g],p1[g]) for g<72; (p0[g]+p1[g])/V for g>=72.
// gh=0 handles g 0..71, gh=1 handles 72..143 -> combine branch is uniform.
// ---------------------------------------------------------------------------
__global__ __launch_bounds__(256) void k2b_mprime(
        const float* __restrict__ part, const float* __restrict__ Wout,
        float* __restrict__ Mp) {
    const int a = blockIdx.x, b = blockIdx.y;
    const int t = threadIdx.x;
    const int nf = t & 127, gh = t >> 7;     // gh = 0/1
    __shared__ float red[2][128];

    const float* p0 = part + (((size_t)0 * BB + b) * AA + a) * TWOF;
    const float* p1 = part + (((size_t)1 * BB + b) * AA + a) * TWOF;
    const float* Wexp = Wout + (size_t)(64 + a * TWOF) * NFF;

    float acc = 0.0f;
    const int g0 = gh * 72;
    if (gh == 0) {
        #pragma unroll 8
        for (int g = 0; g < 72; ++g) {
            const float cg = fmaxf(p0[g], p1[g]);
            acc += cg * Wexp[(size_t)g * NFF + nf];
        }
    } else {
        #pragma unroll 8
        for (int g = 72; g < 144; ++g) {
            const float cg = (p0[g] + p1[g]) * (1.0f / (float)VV);
            acc += cg * Wexp[(size_t)g * NFF + nf];
        }
    }
    (void)g0;
    red[gh][nf] = acc;
    __syncthreads();

    if (t < 128) {
        float r = red[0][t] + red[1][t] + Wout[(size_t)(1216 + a) * NFF + t];
        Mp[((size_t)b * AA + a) * NFF + t] = r;
    }
}

// ---------------------------------------------------------------------------
// k3: out = tanh(x@Wtop + agg@M'[b] + bout)  -> [B][V][NF]
// wave q owns nf cols q*32..q*32+31; lane = vertex. All 32 outputs accumulate
// in registers (acc[8] float4, static-indexed); the 128-B line is stored in
// one back-to-back burst at the end -> no partial-line eviction window.
// ---------------------------------------------------------------------------
__device__ __forceinline__ float fast_tanh(float z) {
    const float e = __expf(2.0f * z);
    return 1.0f - 2.0f / (e + 1.0f);
}

__global__ __launch_bounds__(256) void k3_out(
        const float* __restrict__ x, const float* __restrict__ agg,
        const float* __restrict__ Mp, const float* __restrict__ Wout,
        const float* __restrict__ bout, float* __restrict__ out) {
    const int b    = blockIdx.y;
    const int t    = threadIdx.x;
    const int q    = __builtin_amdgcn_readfirstlane(t >> 6);  // nf-quarter, uniform
    const int lane = t & 63;
    const int v    = blockIdx.x * 64 + lane;
    const int n0   = q * 32;

    const float* Wq  = Wout + n0;                       // rows 0..63, col slice
    const float* Mpq = Mp + (size_t)b * AA * NFF + n0;
    const float* bq  = bout + n0;

    float4 acc[8];
    #pragma unroll
    for (int cc = 0; cc < 8; ++cc)
        acc[cc] = *reinterpret_cast<const float4*>(&bq[4 * cc]);

    // x@Wtop: stream x in float4s; W row slice (128 B) via uniform scalar loads
    const float4* xp = reinterpret_cast<const float4*>(x + ((size_t)b * VV + v) * PP);
    #pragma unroll 4
    for (int i = 0; i < 16; ++i) {
        const float4 xq = xp[i];
        #pragma unroll
        for (int pp = 0; pp < 4; ++pp) {
            const float xv = (pp == 0) ? xq.x : (pp == 1) ? xq.y : (pp == 2) ? xq.z : xq.w;
            const float* wrow = &Wq[(size_t)(4 * i + pp) * NFF];
            #pragma unroll
            for (int cc = 0; cc < 8; ++cc) {
                const float4 wt = *reinterpret_cast<const float4*>(&wrow[4 * cc]);
                acc[cc].x += xv * wt.x; acc[cc].y += xv * wt.y;
                acc[cc].z += xv * wt.z; acc[cc].w += xv * wt.w;
            }
        }
    }

    // agg @ M'[b]
    float e[8];
    const float4* ep = reinterpret_cast<const float4*>(agg + ((size_t)b * VV + v) * AA);
    {
        const float4 e0 = ep[0], e1 = ep[1];
        e[0] = e0.x; e[1] = e0.y; e[2] = e0.z; e[3] = e0.w;
        e[4] = e1.x; e[5] = e1.y; e[6] = e1.z; e[7] = e1.w;
    }
    #pragma unroll
    for (int a = 0; a < 8; ++a) {
        const float ea = e[a];
        const float* mrow = &Mpq[(size_t)a * NFF];
        #pragma unroll
        for (int cc = 0; cc < 8; ++cc) {
            const float4 wt = *reinterpret_cast<const float4*>(&mrow[4 * cc]);
            acc[cc].x += ea * wt.x; acc[cc].y += ea * wt.y;
            acc[cc].z += ea * wt.z; acc[cc].w += ea * wt.w;
        }
    }

    // tanh + burst store (8 x float4 = one full 128-B line, back-to-back)
    float* op = out + ((size_t)b * VV + v) * NFF + n0;
    #pragma unroll
    for (int cc = 0; cc < 8; ++cc) {
        float4 r = acc[cc];
        r.x = fast_tanh(r.x); r.y = fast_tanh(r.y);
        r.z = fast_tanh(r.z); r.w = fast_tanh(r.w);
        acc[cc] = r;
    }
    #pragma unroll
    for (int cc = 0; cc < 8; ++cc)
        *reinterpret_cast<float4*>(&op[4 * cc]) = acc[cc];
}

// ---------------------------------------------------------------------------
extern "C" void kernel_launch(void* const* d_in, const int* in_sizes, int n_in,
                              void* d_out, int out_size, void* d_ws, size_t ws_size,
                              hipStream_t stream) {
    const float* x    = (const float*)d_in[0];
    const float* W1   = (const float*)d_in[1];
    const float* b1   = (const float*)d_in[2];
    const float* W2   = (const float*)d_in[3];
    const float* b2   = (const float*)d_in[4];
    const float* Wout = (const float*)d_in[5];
    const float* bout = (const float*)d_in[6];
    float* out = (float*)d_out;

    float* ws     = (float*)d_ws;
    float* featsT = ws;                                   // B*F*V     = 4,718,592
    float* agg    = featsT + (size_t)BB * FF * VV;        // B*V*A     =   524,288
    float* part   = agg + (size_t)BB * VV * AA;           // 2*B*A*2F  =    73,728
    float* Mp     = part + (size_t)2 * BB * AA * TWOF;    // B*A*NF    =    32,768

    k1_feats<<<dim3(32, 32), dim3(256), 0, stream>>>(x, W1, b1, W2, b2, featsT, agg);
    k2_reduce<<<dim3(36, 32), dim3(256), 0, stream>>>(featsT, agg, part);
    k2b_mprime<<<dim3(8, 32), dim3(256), 0, stream>>>(part, Wout, Mp);
    k3_out<<<dim3(32, 32), dim3(256), 0, stream>>>(x, agg, Mp, Wout, bout, out);
}